// Round 17
// baseline (228.152 us; speedup 1.0000x reference)
//
#include <hip/hip_runtime.h>
#include <hip/hip_bf16.h>
#include <cstdint>

// B=2, N=1024, E=768, H=12, D=64
typedef __attribute__((ext_vector_type(8))) short s16x8;
typedef __attribute__((ext_vector_type(8))) unsigned short u16x8_t;
typedef __attribute__((ext_vector_type(4))) float f32x4_t;
typedef __attribute__((ext_vector_type(4))) unsigned int u32x4_t;
typedef __attribute__((ext_vector_type(2))) unsigned int u32x2_t;
typedef __attribute__((ext_vector_type(4))) unsigned short u16x4_t;

__device__ __forceinline__ unsigned short f2b(float f){
  unsigned u = __float_as_uint(f);
  u += 0x7fffu + ((u>>16)&1u);
  return (unsigned short)(u>>16);
}
__device__ __forceinline__ float b2f(unsigned short s){
  return __uint_as_float(((unsigned)s)<<16);
}
__device__ __forceinline__ float b2f_lo(unsigned u){ return __uint_as_float(u<<16); }
__device__ __forceinline__ float b2f_hi(unsigned u){ return __uint_as_float(u & 0xffff0000u); }
__device__ __forceinline__ unsigned cvt_pk_bf16(float lo, float hi){
  unsigned r;
  asm("v_cvt_pk_bf16_f32 %0, %1, %2" : "=v"(r) : "v"(lo), "v"(hi));
  return r;
}

constexpr float INV_SQRT_E = 0.036084391824351615f; // 1/sqrt(768)
constexpr float LOG2E = 1.4426950408889634f;

// ---------------- f32 -> bf16 conversion (X and stacked weights) ----------------
__global__ void k_convert(const float* __restrict__ X,
                          const float* __restrict__ Wq, const float* __restrict__ Wk,
                          const float* __restrict__ Wv, const float* __restrict__ Wo,
                          unsigned short* __restrict__ Xb, unsigned short* __restrict__ Wst){
  const int64_t WTOT = (int64_t)3072*768/4;
  const int64_t XTOT = (int64_t)2048*768/4;
  for (int64_t i = (int64_t)blockIdx.x*blockDim.x + threadIdx.x; i < WTOT+XTOT;
       i += (int64_t)gridDim.x*blockDim.x){
    const float* src; unsigned short* dst;
    if (i < WTOT){
      int64_t e4 = i*4;
      int j = (int)(e4/768), k = (int)(e4 - (int64_t)j*768);
      int w = j/768; int jr = j - w*768;
      const float* Wsel = (w==0)? Wq : (w==1)? Wk : (w==2)? Wv : Wo;
      src = Wsel + (int64_t)jr*768 + k;
      dst = Wst + e4;
    } else {
      int64_t t = (i-WTOT)*4;
      src = X + t; dst = Xb + t;
    }
    f32x4_t v = *reinterpret_cast<const f32x4_t*>(src);
    u16x4_t o;
    o[0]=f2b(v[0]); o[1]=f2b(v[1]); o[2]=f2b(v[2]); o[3]=f2b(v[3]);
    *reinterpret_cast<u16x4_t*>(dst) = o;
  }
}

// ---------------- bf16 MFMA GEMM, 64x64 tile, 4 waves (2x2), wave-tile 32x32 ----------------
__launch_bounds__(256)
__global__ void k_gemm(const unsigned short* __restrict__ A,
                       const unsigned short* __restrict__ Wst,
                       const int mode,
                       const float* __restrict__ bq, const float* __restrict__ bk,
                       const float* __restrict__ bv, const float* __restrict__ bo,
                       unsigned short* __restrict__ Qb, unsigned short* __restrict__ Kb,
                       unsigned short* __restrict__ Vt, float* __restrict__ Out){
  __shared__ unsigned short As[64*64];
  __shared__ unsigned short Bs[64*64];
  const int tiles_n = (mode==0)?36:12;
  const int tm = blockIdx.x / tiles_n, tn = blockIdx.x % tiles_n;
  const int row0 = tm*64, col0 = tn*64;
  const unsigned short* Bbase = Wst + (mode==0 ? 0 : (int64_t)2304*768);
  const int tid = threadIdx.x;
  const int lane = tid & 63, wvi = tid >> 6;
  const int l15 = lane & 15, lg = lane >> 4;
  const int wr = (wvi>>1)*32, wc = (wvi&1)*32;
  f32x4_t acc[2][2] = {};
  for (int k0=0;k0<768;k0+=64){
    #pragma unroll
    for (int i=0;i<2;i++){
      int t = tid + i*256;
      int r = t>>3, c8 = t&7;
      u32x4_t va = *reinterpret_cast<const u32x4_t*>(A + (int64_t)(row0+r)*768 + k0 + c8*8);
      u32x4_t vb = *reinterpret_cast<const u32x4_t*>(Bbase + (int64_t)(col0+r)*768 + k0 + c8*8);
      int byt = (t*16) ^ ((r&7)<<4);
      *reinterpret_cast<u32x4_t*>(reinterpret_cast<char*>(As)+byt) = va;
      *reinterpret_cast<u32x4_t*>(reinterpret_cast<char*>(Bs)+byt) = vb;
    }
    __syncthreads();
    #pragma unroll
    for (int ks=0;ks<2;ks++){
      s16x8 af[2], bf[2];
      #pragma unroll
      for (int mt=0;mt<2;mt++){
        int r = wr + mt*16 + l15;
        int byt = (r*128 + ks*64 + lg*16) ^ ((r&7)<<4);
        af[mt] = *reinterpret_cast<const s16x8*>(reinterpret_cast<const char*>(As)+byt);
      }
      #pragma unroll
      for (int nt=0;nt<2;nt++){
        int r = wc + nt*16 + l15;
        int byt = (r*128 + ks*64 + lg*16) ^ ((r&7)<<4);
        bf[nt] = *reinterpret_cast<const s16x8*>(reinterpret_cast<const char*>(Bs)+byt);
      }
      #pragma unroll
      for (int mt=0;mt<2;mt++)
        #pragma unroll
        for (int nt=0;nt<2;nt++)
          acc[mt][nt] = __builtin_amdgcn_mfma_f32_16x16x32_bf16(af[mt], bf[nt], acc[mt][nt], 0,0,0);
    }
    __syncthreads();
  }
  #pragma unroll
  for (int mt=0;mt<2;mt++){
    #pragma unroll
    for (int nt=0;nt<2;nt++){
      int j = col0 + wc + nt*16 + l15;
      #pragma unroll
      for (int r=0;r<4;r++){
        int ii = row0 + wr + mt*16 + lg*4 + r;
        float v = acc[mt][nt][r];
        if (mode==0){
          int w = j/768; int e = j - w*768; int h = e>>6, d = e&63;
          int b = ii>>10, n = ii & 1023;
          if (w==0)      Qb[(((int64_t)(b*12+h)*1024)+n)*64+d] = f2b((v + bq[e])*INV_SQRT_E);
          else if (w==1) Kb[(((int64_t)(b*12+h)*1024)+n)*64+d] = f2b(v + bk[e]);
          else           Vt[(((int64_t)(b*12+h)*64)+d)*1024+n] = f2b(v + bv[e]);
        } else {
          Out[(int64_t)ii*768 + j] = v + bo[j];
        }
      }
    }
  }
}

// ---------------- FUSED v10: Pb dropped (P overlays Sq stride-36, bank-safe); 3 blocks/CU ----------------
// grid: (b, qtile16, mchunk128) = 1024 blocks, 256 threads. LDS 41.5KB -> 3 blocks/CU.
// Overlay semantics (verified R9): exp lane reads Sq[eq][h][mg*8..+7] (own-wave h col),
// writes P back to the SAME slots; PV reads Sq[l15][h][lg*8] (own-wave h). Strides
// 72B(h)/864B(q) stagger banks (24-bank step) — the R12 stride-48 conflict is avoided.
__launch_bounds__(256,2)
__global__ void k_fused(const unsigned short* __restrict__ Qb, const unsigned short* __restrict__ Kb,
                        const unsigned short* __restrict__ Vt, const int* __restrict__ adj,
                        const float* __restrict__ Ef,
                        float* __restrict__ Onum, float* __restrict__ Lws){
  __shared__ float Sk[12][16][36];            // 27,648 B : QK scores [h][q][m]
  __shared__ unsigned short Sq[16][12][36];   // 13,824 B : QE scores -> probs (overlay)
  const int bid = blockIdx.x;
  const int mh = bid & 7, qt = (bid>>3) & 63, b = bid >> 9;
  const int q0 = qt*16, mbase = mh*128;
  const int tid = threadIdx.x, lane = tid & 63, wvi = tid>>6;
  const int l15 = lane & 15, lg = lane >> 4;
  const int eq = lane >> 2, mg = lane & 3;    // exp mapping: q=eq, m-octet=mg

  s16x8 afQ[3][2];
  const unsigned short* vB[3];
  const unsigned short* kB[3];
  #pragma unroll
  for (int hh=0;hh<3;hh++){
    const int h = wvi*3+hh;
    const unsigned short* p = Qb + (((int64_t)(b*12+h)*1024) + q0 + l15)*64;
    afQ[hh][0] = *reinterpret_cast<const s16x8*>(p + lg*8);
    afQ[hh][1] = *reinterpret_cast<const s16x8*>(p + 32 + lg*8);
    vB[hh]  = Vt + ((int64_t)(b*12+h)*64)*1024 + mbase + lg*8;
    kB[hh]  = Kb + ((int64_t)(b*12+h)*1024 + mbase + l15)*64;
  }
  s16x8 bfQ[4][2];
  #pragma unroll
  for (int qq=0;qq<4;qq++){
    s16x8 v0 = {}; s16x8 v1 = {};
    if (l15 < 12){
      const unsigned short* p = Qb + (((int64_t)(b*12+l15)*1024) + q0 + wvi*4 + qq)*64;
      v0 = *reinterpret_cast<const s16x8*>(p + lg*8);
      v1 = *reinterpret_cast<const s16x8*>(p + 32 + lg*8);
    }
    bfQ[qq][0]=v0; bfQ[qq][1]=v1;
  }
  const float* efBase = Ef + (((int64_t)b*1024 + q0 + wvi*4)*1024 + mbase + l15)*64 + lg*8;
  const int*  adjBase = adj + ((int64_t)b*1024 + q0 + wvi*4)*1024 + mbase + lg*4;

  f32x4_t accO[3][4] = {};
  float Lp[3] = {0.f,0.f,0.f};
  f32x4_t eBuf0[8], eBuf1[8];

#define LOAD_E(BUF, QQ, SO) { \
    const float* ep_ = efBase + (int64_t)(QQ)*65536 + (SO)*64; \
    BUF[0] = *reinterpret_cast<const f32x4_t*>(ep_);          \
    BUF[1] = *reinterpret_cast<const f32x4_t*>(ep_+4);        \
    BUF[2] = *reinterpret_cast<const f32x4_t*>(ep_+32);       \
    BUF[3] = *reinterpret_cast<const f32x4_t*>(ep_+36);       \
    BUF[4] = *reinterpret_cast<const f32x4_t*>(ep_+1024);     \
    BUF[5] = *reinterpret_cast<const f32x4_t*>(ep_+1028);     \
    BUF[6] = *reinterpret_cast<const f32x4_t*>(ep_+1056);     \
    BUF[7] = *reinterpret_cast<const f32x4_t*>(ep_+1060);     \
  }
#define QE_COMPUTE(BUF, QQ) { \
    _Pragma("unroll") \
    for (int mt2=0;mt2<2;mt2++){ \
      f32x4_t acc = {0.f,0.f,0.f,0.f}; \
      _Pragma("unroll") \
      for (int ks=0;ks<2;ks++){ \
        f32x4_t lo = BUF[mt2*4+ks*2]; \
        f32x4_t hi = BUF[mt2*4+ks*2+1]; \
        u32x4_t ec; \
        ec[0]=cvt_pk_bf16(lo[0],lo[1]); ec[1]=cvt_pk_bf16(lo[2],lo[3]); \
        ec[2]=cvt_pk_bf16(hi[0],hi[1]); ec[3]=cvt_pk_bf16(hi[2],hi[3]); \
        s16x8 ea = __builtin_bit_cast(s16x8, ec); \
        acc = __builtin_amdgcn_mfma_f32_16x16x32_bf16(ea, bfQ[QQ][ks], acc, 0,0,0); \
      } \
      u32x4_t av = *reinterpret_cast<const u32x4_t*>(adjBase + (QQ)*1024 + so + mt2*16); \
      if (l15 < 12){ \
        u16x4_t o; \
        o[0] = av[0] ? f2b(acc[0]) : (unsigned short)0xFF80; \
        o[1] = av[1] ? f2b(acc[1]) : (unsigned short)0xFF80; \
        o[2] = av[2] ? f2b(acc[2]) : (unsigned short)0xFF80; \
        o[3] = av[3] ? f2b(acc[3]) : (unsigned short)0xFF80; \
        *reinterpret_cast<u16x4_t*>(&Sq[wvi*4+(QQ)][l15][mt2*16 + lg*4]) = o; \
      } \
    } \
  }

  // ---- prologue: step 0's qq0/qq1 loads ----
  LOAD_E(eBuf0, 0, 0)
  LOAD_E(eBuf1, 1, 0)

  for (int step=0; step<4; step++){
    const int so = step*32;
    if (step) __syncthreads();                 // guard Sq reuse across steps
    // ---- V prefetch for this step (L2/L3-resident) ----
    s16x8 vC[3][4];
    #pragma unroll
    for (int hh=0;hh<3;hh++)
      #pragma unroll
      for (int dsb=0;dsb<4;dsb++)
        vC[hh][dsb] = *reinterpret_cast<const s16x8*>(vB[hh] + (int64_t)(dsb*16+l15)*1024 + so);
    // ---- QK^T own 3 heads -> Sk[h][q][m] (wave-private); E0/E1 still in flight ----
    #pragma unroll
    for (int hh=0;hh<3;hh++){
      const int h = wvi*3+hh;
      const unsigned short* kp = kB[hh] + so*64;
      #pragma unroll
      for (int mh2=0;mh2<2;mh2++){
        const unsigned short* kr = kp + mh2*16*64;
        f32x4_t a = {0.f,0.f,0.f,0.f};
        s16x8 k0v = *reinterpret_cast<const s16x8*>(kr + lg*8);
        s16x8 k1v = *reinterpret_cast<const s16x8*>(kr + 32 + lg*8);
        a = __builtin_amdgcn_mfma_f32_16x16x32_bf16(afQ[hh][0], k0v, a, 0,0,0);
        a = __builtin_amdgcn_mfma_f32_16x16x32_bf16(afQ[hh][1], k1v, a, 0,0,0);
        #pragma unroll
        for (int r=0;r<4;r++) Sk[h][lg*4+r][mh2*16+l15] = a[r];
      }
    }
    // ---- QE pipeline: consume E0|issue E2; consume E1|issue E3; consume E2,E3 ----
    QE_COMPUTE(eBuf0, 0)
    LOAD_E(eBuf0, 2, so)
    QE_COMPUTE(eBuf1, 1)
    LOAD_E(eBuf1, 3, so)
    QE_COMPUTE(eBuf0, 2)
    QE_COMPUTE(eBuf1, 3)
    // ---- tail: issue NEXT step's E0/E1 -> in flight across barrier+exp+PV ----
    if (step < 3){
      LOAD_E(eBuf0, 0, so+32)
      LOAD_E(eBuf1, 1, so+32)
    }
    __syncthreads();                           // Sq complete for all waves
    // ---- exp: all 64 lanes, own 3 heads; p = exp(Sk + Sq); P overwrites Sq in place ----
    #pragma unroll
    for (int hh=0;hh<3;hh++){
      const int h = wvi*3+hh;
      const float* sr = &Sk[h][eq][mg*8];
      f32x4_t s0 = *reinterpret_cast<const f32x4_t*>(sr);
      f32x4_t s1 = *reinterpret_cast<const f32x4_t*>(sr+4);
      unsigned short* sqp = &Sq[eq][h][mg*8];
      u32x2_t sq0 = *reinterpret_cast<const u32x2_t*>(sqp);
      u32x2_t sq1 = *reinterpret_cast<const u32x2_t*>(sqp+4);
      float p[8];
      p[0] = exp2f((s0[0] + b2f_lo(sq0[0]))*LOG2E);
      p[1] = exp2f((s0[1] + b2f_hi(sq0[0]))*LOG2E);
      p[2] = exp2f((s0[2] + b2f_lo(sq0[1]))*LOG2E);
      p[3] = exp2f((s0[3] + b2f_hi(sq0[1]))*LOG2E);
      p[4] = exp2f((s1[0] + b2f_lo(sq1[0]))*LOG2E);
      p[5] = exp2f((s1[1] + b2f_hi(sq1[0]))*LOG2E);
      p[6] = exp2f((s1[2] + b2f_lo(sq1[1]))*LOG2E);
      p[7] = exp2f((s1[3] + b2f_hi(sq1[1]))*LOG2E);
      Lp[hh] += ((p[0]+p[1])+(p[2]+p[3])) + ((p[4]+p[5])+(p[6]+p[7]));
      u32x2_t w0; w0[0]=cvt_pk_bf16(p[0],p[1]); w0[1]=cvt_pk_bf16(p[2],p[3]);
      *reinterpret_cast<u32x2_t*>(sqp) = w0;
      u32x2_t w1; w1[0]=cvt_pk_bf16(p[4],p[5]); w1[1]=cvt_pk_bf16(p[6],p[7]);
      *reinterpret_cast<u32x2_t*>(sqp+4) = w1;
    }
    // ---- PV own 3 heads (P from Sq overlay, V prefetched) ----
    #pragma unroll
    for (int hh=0;hh<3;hh++){
      const int h = wvi*3+hh;
      const unsigned short* pq = &Sq[l15][h][lg*8];
      u32x2_t a0 = *reinterpret_cast<const u32x2_t*>(pq);
      u32x2_t a1 = *reinterpret_cast<const u32x2_t*>(pq+4);
      u32x4_t pk4; pk4[0]=a0[0]; pk4[1]=a0[1]; pk4[2]=a1[0]; pk4[3]=a1[1];
      s16x8 pa = __builtin_bit_cast(s16x8, pk4);
      #pragma unroll
      for (int dsb=0;dsb<4;dsb++)
        accO[hh][dsb] = __builtin_amdgcn_mfma_f32_16x16x32_bf16(pa, vC[hh][dsb], accO[hh][dsb], 0,0,0);
    }
  }
#undef LOAD_E
#undef QE_COMPUTE
  // ---- write partial numerators + L ----
  float* obase = Onum + (int64_t)(b*8+mh)*12*1024*64;
  #pragma unroll
  for (int hh=0;hh<3;hh++){
    const int h = wvi*3+hh;
    #pragma unroll
    for (int dsb=0;dsb<4;dsb++){
      #pragma unroll
      for (int r=0;r<4;r++)
        obase[((int64_t)h*1024 + q0 + lg*4 + r)*64 + dsb*16 + l15] = accO[hh][dsb][r];
    }
  }
  #pragma unroll
  for (int hh=0;hh<3;hh++){
    float Lr = Lp[hh];
    Lr += __shfl_xor(Lr, 1);
    Lr += __shfl_xor(Lr, 2);
    if (mg==0){
      int64_t idx = (((int64_t)(b*8+mh)*12)+(wvi*3+hh))*1024 + q0 + eq;
      Lws[idx] = Lr;
    }
  }
}

// ---------------- combine 8 m-partials: out = sum(num)/sum(L) ----------------
__global__ void k_combine(const float* __restrict__ Onum, const float* __restrict__ Lws,
                          unsigned short* __restrict__ A2){
  int64_t t = (int64_t)blockIdx.x*blockDim.x + threadIdx.x;
  if (t >= (int64_t)2*12*1024*64) return;
  const int d = (int)(t & 63);
  const int n = (int)((t>>6) & 1023);
  const int hb = (int)(t>>16);
  const int h = hb % 12, b = hb / 12;
  float num = 0.f, L = 0.f;
  #pragma unroll
  for (int p=0;p<8;p++){
    int64_t base = (((int64_t)(b*8+p)*12)+h)*1024 + n;
    L   += Lws[base];
    num += Onum[base*64 + d];
  }
  A2[((int64_t)(b*1024+n))*768 + h*64 + d] = f2b(num/L);
}

extern "C" void kernel_launch(void* const* d_in, const int* in_sizes, int n_in,
                              void* d_out, int out_size, void* d_ws, size_t ws_size,
                              hipStream_t stream){
  const float* X  = (const float*)d_in[0];
  const int*   adj= (const int*)d_in[1];
  const float* Ef = (const float*)d_in[2];
  const float* Wq = (const float*)d_in[3];
  const float* bq = (const float*)d_in[4];
  const float* Wk = (const float*)d_in[5];
  const float* bk = (const float*)d_in[6];
  const float* Wv = (const float*)d_in[7];
  const float* bv = (const float*)d_in[8];
  const float* Wo = (const float*)d_in[9];
  const float* bo = (const float*)d_in[10];
  char* w = (char*)d_ws;
  unsigned short* Xb = (unsigned short*)(w);
  unsigned short* Wst= (unsigned short*)(w + 3145728);
  unsigned short* Qb = (unsigned short*)(w + 7864320);
  unsigned short* Kb = (unsigned short*)(w + 11010048);
  unsigned short* Vt = (unsigned short*)(w + 14155776);
  float* Onum        = (float*)(w + 67633152);    // 50,331,648 (B,8,H,N,D) f32
  float* Lws         = (float*)(w + 117964800);   // 786,432
  unsigned short* A2 = (unsigned short*)(w + 118751232);
  float* Out = (float*)d_out;

  k_convert<<<3840,256,0,stream>>>(X,Wq,Wk,Wv,Wo,Xb,Wst);
  k_gemm<<<1152,256,0,stream>>>(Xb,Wst,0,bq,bk,bv,bo,Qb,Kb,Vt,nullptr);
  k_fused<<<1024,256,0,stream>>>(Qb,Kb,Vt,adj,Ef,Onum,Lws);
  k_combine<<<6144,256,0,stream>>>(Onum,Lws,A2);
  k_gemm<<<384,256,0,stream>>>(A2,Wst,1,bq,bk,bv,bo,nullptr,nullptr,nullptr,Out);
}

// Round 18
// 217.890 us; speedup vs baseline: 1.0471x; 1.0471x over previous
//
#include <hip/hip_runtime.h>
#include <hip/hip_bf16.h>
#include <cstdint>

// B=2, N=1024, E=768, H=12, D=64
typedef __attribute__((ext_vector_type(8))) short s16x8;
typedef __attribute__((ext_vector_type(8))) unsigned short u16x8_t;
typedef __attribute__((ext_vector_type(4))) float f32x4_t;
typedef __attribute__((ext_vector_type(4))) unsigned int u32x4_t;
typedef __attribute__((ext_vector_type(4))) unsigned short u16x4_t;

__device__ __forceinline__ unsigned short f2b(float f){
  unsigned u = __float_as_uint(f);
  u += 0x7fffu + ((u>>16)&1u);
  return (unsigned short)(u>>16);
}
__device__ __forceinline__ float b2f(unsigned short s){
  return __uint_as_float(((unsigned)s)<<16);
}
__device__ __forceinline__ unsigned cvt_pk_bf16(float lo, float hi){
  unsigned r;
  asm("v_cvt_pk_bf16_f32 %0, %1, %2" : "=v"(r) : "v"(lo), "v"(hi));
  return r;
}

constexpr float INV_SQRT_E = 0.036084391824351615f; // 1/sqrt(768)
constexpr float LOG2E = 1.4426950408889634f;

// ---------------- f32 -> bf16 conversion (X and stacked weights) ----------------
__global__ void k_convert(const float* __restrict__ X,
                          const float* __restrict__ Wq, const float* __restrict__ Wk,
                          const float* __restrict__ Wv, const float* __restrict__ Wo,
                          unsigned short* __restrict__ Xb, unsigned short* __restrict__ Wst){
  const int64_t WTOT = (int64_t)3072*768/4;
  const int64_t XTOT = (int64_t)2048*768/4;
  for (int64_t i = (int64_t)blockIdx.x*blockDim.x + threadIdx.x; i < WTOT+XTOT;
       i += (int64_t)gridDim.x*blockDim.x){
    const float* src; unsigned short* dst;
    if (i < WTOT){
      int64_t e4 = i*4;
      int j = (int)(e4/768), k = (int)(e4 - (int64_t)j*768);
      int w = j/768; int jr = j - w*768;
      const float* Wsel = (w==0)? Wq : (w==1)? Wk : (w==2)? Wv : Wo;
      src = Wsel + (int64_t)jr*768 + k;
      dst = Wst + e4;
    } else {
      int64_t t = (i-WTOT)*4;
      src = X + t; dst = Xb + t;
    }
    f32x4_t v = *reinterpret_cast<const f32x4_t*>(src);
    u16x4_t o;
    o[0]=f2b(v[0]); o[1]=f2b(v[1]); o[2]=f2b(v[2]); o[3]=f2b(v[3]);
    *reinterpret_cast<u16x4_t*>(dst) = o;
  }
}

// ---------------- bf16 MFMA GEMM, 64x64 tile, 4 waves (2x2), wave-tile 32x32 ----------------
__launch_bounds__(256)
__global__ void k_gemm(const unsigned short* __restrict__ A,
                       const unsigned short* __restrict__ Wst,
                       const int mode,
                       const float* __restrict__ bq, const float* __restrict__ bk,
                       const float* __restrict__ bv, const float* __restrict__ bo,
                       unsigned short* __restrict__ Qb, unsigned short* __restrict__ Kb,
                       unsigned short* __restrict__ Vt, float* __restrict__ Out){
  __shared__ unsigned short As[64*64];
  __shared__ unsigned short Bs[64*64];
  const int tiles_n = (mode==0)?36:12;
  const int tm = blockIdx.x / tiles_n, tn = blockIdx.x % tiles_n;
  const int row0 = tm*64, col0 = tn*64;
  const unsigned short* Bbase = Wst + (mode==0 ? 0 : (int64_t)2304*768);
  const int tid = threadIdx.x;
  const int lane = tid & 63, wvi = tid >> 6;
  const int l15 = lane & 15, lg = lane >> 4;
  const int wr = (wvi>>1)*32, wc = (wvi&1)*32;
  f32x4_t acc[2][2] = {};
  for (int k0=0;k0<768;k0+=64){
    #pragma unroll
    for (int i=0;i<2;i++){
      int t = tid + i*256;
      int r = t>>3, c8 = t&7;
      u32x4_t va = *reinterpret_cast<const u32x4_t*>(A + (int64_t)(row0+r)*768 + k0 + c8*8);
      u32x4_t vb = *reinterpret_cast<const u32x4_t*>(Bbase + (int64_t)(col0+r)*768 + k0 + c8*8);
      int byt = (t*16) ^ ((r&7)<<4);
      *reinterpret_cast<u32x4_t*>(reinterpret_cast<char*>(As)+byt) = va;
      *reinterpret_cast<u32x4_t*>(reinterpret_cast<char*>(Bs)+byt) = vb;
    }
    __syncthreads();
    #pragma unroll
    for (int ks=0;ks<2;ks++){
      s16x8 af[2], bf[2];
      #pragma unroll
      for (int mt=0;mt<2;mt++){
        int r = wr + mt*16 + l15;
        int byt = (r*128 + ks*64 + lg*16) ^ ((r&7)<<4);
        af[mt] = *reinterpret_cast<const s16x8*>(reinterpret_cast<const char*>(As)+byt);
      }
      #pragma unroll
      for (int nt=0;nt<2;nt++){
        int r = wc + nt*16 + l15;
        int byt = (r*128 + ks*64 + lg*16) ^ ((r&7)<<4);
        bf[nt] = *reinterpret_cast<const s16x8*>(reinterpret_cast<const char*>(Bs)+byt);
      }
      #pragma unroll
      for (int mt=0;mt<2;mt++)
        #pragma unroll
        for (int nt=0;nt<2;nt++)
          acc[mt][nt] = __builtin_amdgcn_mfma_f32_16x16x32_bf16(af[mt], bf[nt], acc[mt][nt], 0,0,0);
    }
    __syncthreads();
  }
  #pragma unroll
  for (int mt=0;mt<2;mt++){
    #pragma unroll
    for (int nt=0;nt<2;nt++){
      int j = col0 + wc + nt*16 + l15;
      #pragma unroll
      for (int r=0;r<4;r++){
        int ii = row0 + wr + mt*16 + lg*4 + r;
        float v = acc[mt][nt][r];
        if (mode==0){
          int w = j/768; int e = j - w*768; int h = e>>6, d = e&63;
          int b = ii>>10, n = ii & 1023;
          if (w==0)      Qb[(((int64_t)(b*12+h)*1024)+n)*64+d] = f2b((v + bq[e])*INV_SQRT_E);
          else if (w==1) Kb[(((int64_t)(b*12+h)*1024)+n)*64+d] = f2b(v + bk[e]);
          else           Vt[(((int64_t)(b*12+h)*64)+d)*1024+n] = f2b(v + bv[e]);
        } else {
          Out[(int64_t)ii*768 + j] = v + bo[j];
        }
      }
    }
  }
}

// ---------------- FUSED v9 (round-16 best): m-partials 4, 256-m chunks, 8 steps ----------------
// grid: (b, qtile16, mchunk256) = 512 blocks = exactly 2 blocks/CU, 256 threads.
__launch_bounds__(256,2)
__global__ void k_fused(const unsigned short* __restrict__ Qb, const unsigned short* __restrict__ Kb,
                        const unsigned short* __restrict__ Vt, const int* __restrict__ adj,
                        const float* __restrict__ Ef,
                        float* __restrict__ Onum, float* __restrict__ Lws){
  __shared__ float Sk[12][16][36];            // 27,648 B : QK scores [h][q][m]
  __shared__ unsigned short Sq[16][12][48];   // 18,432 B : QE scores [q][h][m] bf16 (-inf masked)
  __shared__ unsigned short Pb[12][16][32];   // 12,288 B : probs [h][q][m] bf16
  const int bid = blockIdx.x;
  const int mh = bid & 3, qt = (bid>>2) & 63, b = bid >> 8;
  const int q0 = qt*16, mbase = mh*256;
  const int tid = threadIdx.x, lane = tid & 63, wvi = tid>>6;
  const int l15 = lane & 15, lg = lane >> 4;
  const int eq = lane >> 2, mg = lane & 3;    // exp mapping: q=eq, m-octet=mg

  s16x8 afQ[3][2];
  const unsigned short* vB[3];
  const unsigned short* kB[3];
  #pragma unroll
  for (int hh=0;hh<3;hh++){
    const int h = wvi*3+hh;
    const unsigned short* p = Qb + (((int64_t)(b*12+h)*1024) + q0 + l15)*64;
    afQ[hh][0] = *reinterpret_cast<const s16x8*>(p + lg*8);
    afQ[hh][1] = *reinterpret_cast<const s16x8*>(p + 32 + lg*8);
    vB[hh]  = Vt + ((int64_t)(b*12+h)*64)*1024 + mbase + lg*8;
    kB[hh]  = Kb + ((int64_t)(b*12+h)*1024 + mbase + l15)*64;
  }
  s16x8 bfQ[4][2];
  #pragma unroll
  for (int qq=0;qq<4;qq++){
    s16x8 v0 = {}; s16x8 v1 = {};
    if (l15 < 12){
      const unsigned short* p = Qb + (((int64_t)(b*12+l15)*1024) + q0 + wvi*4 + qq)*64;
      v0 = *reinterpret_cast<const s16x8*>(p + lg*8);
      v1 = *reinterpret_cast<const s16x8*>(p + 32 + lg*8);
    }
    bfQ[qq][0]=v0; bfQ[qq][1]=v1;
  }
  const float* efBase = Ef + (((int64_t)b*1024 + q0 + wvi*4)*1024 + mbase + l15)*64 + lg*8;
  const int*  adjBase = adj + ((int64_t)b*1024 + q0 + wvi*4)*1024 + mbase + lg*4;

  f32x4_t accO[3][4] = {};
  float Lp[3] = {0.f,0.f,0.f};
  f32x4_t eBuf0[8], eBuf1[8];

#define LOAD_E(BUF, QQ, SO) { \
    const float* ep_ = efBase + (int64_t)(QQ)*65536 + (SO)*64; \
    BUF[0] = *reinterpret_cast<const f32x4_t*>(ep_);          \
    BUF[1] = *reinterpret_cast<const f32x4_t*>(ep_+4);        \
    BUF[2] = *reinterpret_cast<const f32x4_t*>(ep_+32);       \
    BUF[3] = *reinterpret_cast<const f32x4_t*>(ep_+36);       \
    BUF[4] = *reinterpret_cast<const f32x4_t*>(ep_+1024);     \
    BUF[5] = *reinterpret_cast<const f32x4_t*>(ep_+1028);     \
    BUF[6] = *reinterpret_cast<const f32x4_t*>(ep_+1056);     \
    BUF[7] = *reinterpret_cast<const f32x4_t*>(ep_+1060);     \
  }
#define QE_COMPUTE(BUF, QQ) { \
    _Pragma("unroll") \
    for (int mt2=0;mt2<2;mt2++){ \
      f32x4_t acc = {0.f,0.f,0.f,0.f}; \
      _Pragma("unroll") \
      for (int ks=0;ks<2;ks++){ \
        f32x4_t lo = BUF[mt2*4+ks*2]; \
        f32x4_t hi = BUF[mt2*4+ks*2+1]; \
        u32x4_t ec; \
        ec[0]=cvt_pk_bf16(lo[0],lo[1]); ec[1]=cvt_pk_bf16(lo[2],lo[3]); \
        ec[2]=cvt_pk_bf16(hi[0],hi[1]); ec[3]=cvt_pk_bf16(hi[2],hi[3]); \
        s16x8 ea = __builtin_bit_cast(s16x8, ec); \
        acc = __builtin_amdgcn_mfma_f32_16x16x32_bf16(ea, bfQ[QQ][ks], acc, 0,0,0); \
      } \
      u32x4_t av = *reinterpret_cast<const u32x4_t*>(adjBase + (QQ)*1024 + so + mt2*16); \
      if (l15 < 12){ \
        u16x4_t o; \
        o[0] = av[0] ? f2b(acc[0]) : (unsigned short)0xFF80; \
        o[1] = av[1] ? f2b(acc[1]) : (unsigned short)0xFF80; \
        o[2] = av[2] ? f2b(acc[2]) : (unsigned short)0xFF80; \
        o[3] = av[3] ? f2b(acc[3]) : (unsigned short)0xFF80; \
        *reinterpret_cast<u16x4_t*>(&Sq[wvi*4+(QQ)][l15][mt2*16 + lg*4]) = o; \
      } \
    } \
  }

  // ---- prologue: step 0's qq0/qq1 loads ----
  LOAD_E(eBuf0, 0, 0)
  LOAD_E(eBuf1, 1, 0)

  for (int step=0; step<8; step++){
    const int so = step*32;
    if (step) __syncthreads();                 // guard Sq reuse across steps
    // ---- V prefetch for this step (L2/L3-resident) ----
    s16x8 vC[3][4];
    #pragma unroll
    for (int hh=0;hh<3;hh++)
      #pragma unroll
      for (int dsb=0;dsb<4;dsb++)
        vC[hh][dsb] = *reinterpret_cast<const s16x8*>(vB[hh] + (int64_t)(dsb*16+l15)*1024 + so);
    // ---- QK^T own 3 heads -> Sk[h][q][m] (wave-private); E0/E1 still in flight ----
    #pragma unroll
    for (int hh=0;hh<3;hh++){
      const int h = wvi*3+hh;
      const unsigned short* kp = kB[hh] + so*64;
      #pragma unroll
      for (int mh2=0;mh2<2;mh2++){
        const unsigned short* kr = kp + mh2*16*64;
        f32x4_t a = {0.f,0.f,0.f,0.f};
        s16x8 k0v = *reinterpret_cast<const s16x8*>(kr + lg*8);
        s16x8 k1v = *reinterpret_cast<const s16x8*>(kr + 32 + lg*8);
        a = __builtin_amdgcn_mfma_f32_16x16x32_bf16(afQ[hh][0], k0v, a, 0,0,0);
        a = __builtin_amdgcn_mfma_f32_16x16x32_bf16(afQ[hh][1], k1v, a, 0,0,0);
        #pragma unroll
        for (int r=0;r<4;r++) Sk[h][lg*4+r][mh2*16+l15] = a[r];
      }
    }
    // ---- QE pipeline: consume E0|issue E2; consume E1|issue E3; consume E2,E3 ----
    QE_COMPUTE(eBuf0, 0)
    LOAD_E(eBuf0, 2, so)
    QE_COMPUTE(eBuf1, 1)
    LOAD_E(eBuf1, 3, so)
    QE_COMPUTE(eBuf0, 2)
    QE_COMPUTE(eBuf1, 3)
    // ---- tail: issue NEXT step's E0/E1 -> in flight across barrier+exp+PV ----
    if (step < 7){
      LOAD_E(eBuf0, 0, so+32)
      LOAD_E(eBuf1, 1, so+32)
    }
    __syncthreads();                           // Sq complete for all waves
    // ---- exp: all 64 lanes, own 3 heads; p = exp(Sk + Sq) ----
    #pragma unroll
    for (int hh=0;hh<3;hh++){
      const int h = wvi*3+hh;
      const float* sr = &Sk[h][eq][mg*8];
      f32x4_t s0 = *reinterpret_cast<const f32x4_t*>(sr);
      f32x4_t s1 = *reinterpret_cast<const f32x4_t*>(sr+4);
      u16x8_t sq = *reinterpret_cast<const u16x8_t*>(&Sq[eq][h][mg*8]);
      float p[8];
      #pragma unroll
      for (int j=0;j<4;j++) p[j]   = exp2f((s0[j] + b2f(sq[j]))*LOG2E);
      #pragma unroll
      for (int j=0;j<4;j++) p[4+j] = exp2f((s1[j] + b2f(sq[4+j]))*LOG2E);
      Lp[hh] += ((p[0]+p[1])+(p[2]+p[3])) + ((p[4]+p[5])+(p[6]+p[7]));
      u32x4_t pk;
      pk[0]=cvt_pk_bf16(p[0],p[1]); pk[1]=cvt_pk_bf16(p[2],p[3]);
      pk[2]=cvt_pk_bf16(p[4],p[5]); pk[3]=cvt_pk_bf16(p[6],p[7]);
      *reinterpret_cast<u32x4_t*>(&Pb[h][eq][mg*8]) = pk;
    }
    // ---- PV own 3 heads (V prefetched) ----
    #pragma unroll
    for (int hh=0;hh<3;hh++){
      const int h = wvi*3+hh;
      s16x8 pa = *reinterpret_cast<const s16x8*>(&Pb[h][l15][lg*8]);
      #pragma unroll
      for (int dsb=0;dsb<4;dsb++)
        accO[hh][dsb] = __builtin_amdgcn_mfma_f32_16x16x32_bf16(pa, vC[hh][dsb], accO[hh][dsb], 0,0,0);
    }
  }
#undef LOAD_E
#undef QE_COMPUTE
  // ---- write partial numerators + L ----
  float* obase = Onum + (int64_t)(b*4+mh)*12*1024*64;
  #pragma unroll
  for (int hh=0;hh<3;hh++){
    const int h = wvi*3+hh;
    #pragma unroll
    for (int dsb=0;dsb<4;dsb++){
      #pragma unroll
      for (int r=0;r<4;r++)
        obase[((int64_t)h*1024 + q0 + lg*4 + r)*64 + dsb*16 + l15] = accO[hh][dsb][r];
    }
  }
  #pragma unroll
  for (int hh=0;hh<3;hh++){
    float Lr = Lp[hh];
    Lr += __shfl_xor(Lr, 1);
    Lr += __shfl_xor(Lr, 2);
    if (mg==0){
      int64_t idx = (((int64_t)(b*4+mh)*12)+(wvi*3+hh))*1024 + q0 + eq;
      Lws[idx] = Lr;
    }
  }
}

// ---------------- combine 4 m-partials, 4 d-elems/thread (f32x4 reads, 16B/lane) ----------------
__global__ void k_combine(const float* __restrict__ Onum, const float* __restrict__ Lws,
                          unsigned short* __restrict__ A2){
  int64_t t = (int64_t)blockIdx.x*blockDim.x + threadIdx.x;
  if (t >= (int64_t)2*12*1024*16) return;
  const int d4 = (int)(t & 15) * 4;
  const int n  = (int)((t>>4) & 1023);
  const int hb = (int)(t>>14);
  const int h = hb % 12, b = hb / 12;
  f32x4_t num = {0.f,0.f,0.f,0.f};
  float L = 0.f;
  #pragma unroll
  for (int p=0;p<4;p++){
    int64_t base = (((int64_t)(b*4+p)*12)+h)*1024 + n;
    L += Lws[base];
    f32x4_t v = *reinterpret_cast<const f32x4_t*>(Onum + base*64 + d4);
    num[0]+=v[0]; num[1]+=v[1]; num[2]+=v[2]; num[3]+=v[3];
  }
  const float rL = 1.0f / L;
  u16x4_t o;
  o[0]=f2b(num[0]*L==0.f?0.f:num[0]/L); // guard never hit (L>0: self-loop); keep exact div
  o[0]=f2b(num[0]/L); o[1]=f2b(num[1]/L); o[2]=f2b(num[2]/L); o[3]=f2b(num[3]/L);
  (void)rL;
  *reinterpret_cast<u16x4_t*>(A2 + ((int64_t)(b*1024+n))*768 + h*64 + d4) = o;
}

extern "C" void kernel_launch(void* const* d_in, const int* in_sizes, int n_in,
                              void* d_out, int out_size, void* d_ws, size_t ws_size,
                              hipStream_t stream){
  const float* X  = (const float*)d_in[0];
  const int*   adj= (const int*)d_in[1];
  const float* Ef = (const float*)d_in[2];
  const float* Wq = (const float*)d_in[3];
  const float* bq = (const float*)d_in[4];
  const float* Wk = (const float*)d_in[5];
  const float* bk = (const float*)d_in[6];
  const float* Wv = (const float*)d_in[7];
  const float* bv = (const float*)d_in[8];
  const float* Wo = (const float*)d_in[9];
  const float* bo = (const float*)d_in[10];
  char* w = (char*)d_ws;
  unsigned short* Xb = (unsigned short*)(w);
  unsigned short* Wst= (unsigned short*)(w + 3145728);
  unsigned short* Qb = (unsigned short*)(w + 7864320);
  unsigned short* Kb = (unsigned short*)(w + 11010048);
  unsigned short* Vt = (unsigned short*)(w + 14155776);
  float* Onum        = (float*)(w + 67633152);    // 25,165,824 (B,4,H,N,D) f32
  float* Lws         = (float*)(w + 117964800);   // 393,216
  unsigned short* A2 = (unsigned short*)(w + 118751232);
  float* Out = (float*)d_out;

  k_convert<<<3840,256,0,stream>>>(X,Wq,Wk,Wv,Wo,Xb,Wst);
  k_gemm<<<1152,256,0,stream>>>(Xb,Wst,0,bq,bk,bv,bo,Qb,Kb,Vt,nullptr);
  k_fused<<<512,256,0,stream>>>(Qb,Kb,Vt,adj,Ef,Onum,Lws);
  k_combine<<<1536,256,0,stream>>>(Onum,Lws,A2);
  k_gemm<<<384,256,0,stream>>>(A2,Wst,1,bq,bk,bv,bo,nullptr,nullptr,nullptr,Out);
}